// Round 4
// baseline (855.847 us; speedup 1.0000x reference)
//
#include <hip/hip_runtime.h>
#include <hip/hip_bf16.h>

typedef __attribute__((ext_vector_type(8))) short bf16x8;
typedef __attribute__((ext_vector_type(4))) float f32x4;

#define HDIM 512
#define BM 128
#define BN 256

__device__ __forceinline__ unsigned short f2bf(float f) {
  unsigned u = __float_as_uint(f);
  u += 0x7fffu + ((u >> 16) & 1u);   // round-to-nearest-even
  return (unsigned short)(u >> 16);
}

__device__ __forceinline__ unsigned int pk_bf(float x, float y) {
  __hip_bfloat162 h = __float22bfloat162_rn(float2{x, y});
  union { __hip_bfloat162 b; unsigned int u; } cv; cv.b = h;
  return cv.u;
}

__device__ __forceinline__ float blo(unsigned int u) { return __uint_as_float(u << 16); }
__device__ __forceinline__ float bhi(unsigned int u) { return __uint_as_float(u & 0xffff0000u); }

// w1 [1024][512] fp32 -> w1t [512][1024] bf16 (transposed so B-frags read contiguous k)
__global__ void k_w1t(const float* __restrict__ w1, unsigned short* __restrict__ w1t) {
  int idx = blockIdx.x * 256 + threadIdx.x;   // exactly 1024*512 threads
  int k = idx >> 9;
  int n = idx & 511;
  w1t[n * 1024 + k] = f2bf(w1[idx]);
}

// C[M,512](bf16) = A[M,512](fp32) @ w1t[:, koff:koff+512]^T   (bf16 MFMA, fp32 acc)
// NO-LDS register GEMM: round-3 counters showed traffic at compulsory floor but
// MfmaUtil 19% with 2 barriers/K-step + 9.6M LDS bank conflicts + staging VALU.
// Neither operand needs LDS cooperation here: A-frag global reads are sector-coalesced
// (16 rows x 128B contiguous per step, x4 wn-reuse served by same-CU L1; 2nd N-block
// via shared L3) and B (1 MB total) is L2-resident. So: zero LDS, zero barriers;
// each wave streams frags global->reg (A cvt fp32->bf16 in-reg) and MFMAs freely.
// Latency hidden by 12 in-flight loads/step x unroll 2 x ~12 waves/CU.
__global__ __launch_bounds__(512) void k_gemm(
    const float* __restrict__ zu, int MU,
    const float* __restrict__ zm, int MM,
    const unsigned short* __restrict__ w1t,
    unsigned short* __restrict__ u1, unsigned short* __restrict__ m1,
    int nMB1)
{
  const int lane = threadIdx.x & 63;
  const int wid  = threadIdx.x >> 6;          // 0..7
  const int wm = wid & 1, wn = wid >> 1;      // 2 x 4 wave grid
  const int lm = lane & 15, lq = lane >> 4;

  const float* A; unsigned short* C; int M, koff, mb = blockIdx.y;
  if (mb < nMB1) { A = zu; C = u1; M = MU; koff = 0; }
  else           { A = zm; C = m1; M = MM; koff = HDIM; mb -= nMB1; }
  const int nbase = blockIdx.x * BN;          // 2 N-blocks, co-scheduled -> share A via L3
  const int mbase = mb * BM;

  // per-lane fragment base pointers (loop-invariant; K-step offsets fold to imm)
  const float* ab[4];
  #pragma unroll
  for (int mi = 0; mi < 4; ++mi) {
    int row = mbase + wm * 64 + mi * 16 + lm; if (row > M - 1) row = M - 1;
    ab[mi] = A + (size_t)row * HDIM + lq * 8;
  }
  const unsigned short* bb[4];
  #pragma unroll
  for (int ni = 0; ni < 4; ++ni) {
    int col = nbase + wn * 64 + ni * 16 + lm;
    bb[ni] = w1t + (size_t)col * 1024 + koff + lq * 8;
  }

  f32x4 acc[4][4];
  #pragma unroll
  for (int i = 0; i < 4; ++i)
    #pragma unroll
    for (int j = 0; j < 4; ++j) acc[i][j] = (f32x4){0.f, 0.f, 0.f, 0.f};

  // 16 K-steps of 32; unroll 2 so next step's 12 loads issue under current MFMAs
  #pragma unroll 2
  for (int s = 0; s < 16; ++s) {
    bf16x8 bfr[4];
    #pragma unroll
    for (int ni = 0; ni < 4; ++ni) bfr[ni] = *(const bf16x8*)(bb[ni] + s * 32);
    float4 v0[4], v1[4];
    #pragma unroll
    for (int mi = 0; mi < 4; ++mi) {
      v0[mi] = *(const float4*)(ab[mi] + s * 32);
      v1[mi] = *(const float4*)(ab[mi] + s * 32 + 4);
    }
    #pragma unroll
    for (int mi = 0; mi < 4; ++mi) {
      bf16x8 af; unsigned int* aw = (unsigned int*)&af;
      aw[0] = pk_bf(v0[mi].x, v0[mi].y); aw[1] = pk_bf(v0[mi].z, v0[mi].w);
      aw[2] = pk_bf(v1[mi].x, v1[mi].y); aw[3] = pk_bf(v1[mi].z, v1[mi].w);
      #pragma unroll
      for (int ni = 0; ni < 4; ++ni)
        acc[mi][ni] = __builtin_amdgcn_mfma_f32_16x16x32_bf16(af, bfr[ni], acc[mi][ni], 0, 0, 0);
    }
  }

  // epilogue: C/D layout col=lane&15, row=(lane>>4)*4+reg  (m89-verified)
  #pragma unroll
  for (int mi = 0; mi < 4; ++mi)
    #pragma unroll
    for (int ni = 0; ni < 4; ++ni)
      #pragma unroll
      for (int r = 0; r < 4; ++r) {
        int rg = mbase + wm * 64 + mi * 16 + lq * 4 + r;
        int cg = nbase + wn * 64 + ni * 16 + lm;
        if (rg < M) C[(size_t)rg * HDIM + cg] = f2bf(acc[mi][ni][r]);
      }
}

// per edge: out = relu(U[row]+M[col]+b1) . w2 + b2 ; one wave, 4 edges/iter
// (8 gather loads in flight vs 4 -- kernel is latency-bound: VALU 30%, HBM 39%)
__global__ __launch_bounds__(256) void k_edge(const int* __restrict__ er, const int* __restrict__ ec,
    const unsigned short* __restrict__ u1, const unsigned short* __restrict__ m1,
    const float* __restrict__ b1, const float* __restrict__ w2, const float* __restrict__ b2,
    float* __restrict__ out, int E)
{
  const int lane = threadIdx.x & 63;
  const int gwid = blockIdx.x * 4 + (threadIdx.x >> 6);
  const int nw   = gridDim.x * 4;
  const float4 b1a = *(const float4*)&b1[lane * 8];
  const float4 b1b = *(const float4*)&b1[lane * 8 + 4];
  const float4 w2a = *(const float4*)&w2[lane * 8];
  const float4 w2b = *(const float4*)&w2[lane * 8 + 4];
  const float bias2 = b2[0];
  for (int e = gwid * 4; e < E; e += nw * 4) {
    if (e + 3 < E) {
      uint4 ua[4], va[4];
      #pragma unroll
      for (int j = 0; j < 4; ++j) {
        ua[j] = *(const uint4*)&u1[(size_t)er[e + j] * HDIM + lane * 8];
        va[j] = *(const uint4*)&m1[(size_t)ec[e + j] * HDIM + lane * 8];
      }
      float p[4];
      #pragma unroll
      for (int j = 0; j < 4; ++j) {
        float pj = 0.f, s;
        s = blo(ua[j].x) + blo(va[j].x) + b1a.x; s = fmaxf(s, 0.f); pj += s * w2a.x;
        s = bhi(ua[j].x) + bhi(va[j].x) + b1a.y; s = fmaxf(s, 0.f); pj += s * w2a.y;
        s = blo(ua[j].y) + blo(va[j].y) + b1a.z; s = fmaxf(s, 0.f); pj += s * w2a.z;
        s = bhi(ua[j].y) + bhi(va[j].y) + b1a.w; s = fmaxf(s, 0.f); pj += s * w2a.w;
        s = blo(ua[j].z) + blo(va[j].z) + b1b.x; s = fmaxf(s, 0.f); pj += s * w2b.x;
        s = bhi(ua[j].z) + bhi(va[j].z) + b1b.y; s = fmaxf(s, 0.f); pj += s * w2b.y;
        s = blo(ua[j].w) + blo(va[j].w) + b1b.z; s = fmaxf(s, 0.f); pj += s * w2b.z;
        s = bhi(ua[j].w) + bhi(va[j].w) + b1b.w; s = fmaxf(s, 0.f); pj += s * w2b.w;
        p[j] = pj;
      }
      #pragma unroll
      for (int off = 32; off > 0; off >>= 1)
        #pragma unroll
        for (int j = 0; j < 4; ++j) p[j] += __shfl_down(p[j], off, 64);
      if (lane == 0)
        *(float4*)&out[e] = float4{p[0] + bias2, p[1] + bias2, p[2] + bias2, p[3] + bias2};
    } else {
      for (int j = 0; j < 4 && e + j < E; ++j) {
        const uint4 ua = *(const uint4*)&u1[(size_t)er[e + j] * HDIM + lane * 8];
        const uint4 va = *(const uint4*)&m1[(size_t)ec[e + j] * HDIM + lane * 8];
        float pj = 0.f, s;
        s = blo(ua.x) + blo(va.x) + b1a.x; s = fmaxf(s, 0.f); pj += s * w2a.x;
        s = bhi(ua.x) + bhi(va.x) + b1a.y; s = fmaxf(s, 0.f); pj += s * w2a.y;
        s = blo(ua.y) + blo(va.y) + b1a.z; s = fmaxf(s, 0.f); pj += s * w2a.z;
        s = bhi(ua.y) + bhi(va.y) + b1a.w; s = fmaxf(s, 0.f); pj += s * w2a.w;
        s = blo(ua.z) + blo(va.z) + b1b.x; s = fmaxf(s, 0.f); pj += s * w2b.x;
        s = bhi(ua.z) + bhi(va.z) + b1b.y; s = fmaxf(s, 0.f); pj += s * w2b.y;
        s = blo(ua.w) + blo(va.w) + b1b.z; s = fmaxf(s, 0.f); pj += s * w2b.z;
        s = bhi(ua.w) + bhi(va.w) + b1b.w; s = fmaxf(s, 0.f); pj += s * w2b.w;
        #pragma unroll
        for (int off = 32; off > 0; off >>= 1) pj += __shfl_down(pj, off, 64);
        if (lane == 0) out[e + j] = pj + bias2;
      }
    }
  }
}

// Correct-but-slow fp32 fallback (only if ws_size too small): fused tiled GEMM
__global__ __launch_bounds__(256) void k_fallback(const float* __restrict__ zu, const float* __restrict__ zm,
    const int* __restrict__ er, const int* __restrict__ ec, const float* __restrict__ w1,
    const float* __restrict__ b1, const float* __restrict__ w2, const float* __restrict__ b2,
    float* __restrict__ out, int E)
{
  __shared__ float Zs[64][33];
  __shared__ float Ws[32][65];
  __shared__ float outacc[64];
  __shared__ int ridx[64], cidx[64];
  const int tid = threadIdx.x;
  const int ebase = blockIdx.x * 64;
  if (tid < 64) {
    int e = ebase + tid; if (e > E - 1) e = E - 1;
    ridx[tid] = er[e]; cidx[tid] = ec[e];
    outacc[tid] = 0.f;
  }
  const int tx = tid & 15, ty = tid >> 4;
  for (int nt = 0; nt < 8; ++nt) {
    float acc[4][4] = {};
    for (int kc = 0; kc < 32; ++kc) {
      __syncthreads();
      #pragma unroll
      for (int i = 0; i < 8; ++i) {
        int id = i * 256 + tid;
        int rr = id >> 5, cc = id & 31;
        int k = kc * 32 + cc;
        Zs[rr][cc] = (k < 512) ? zu[(size_t)ridx[rr] * 512 + k]
                               : zm[(size_t)cidx[rr] * 512 + (k - 512)];
      }
      #pragma unroll
      for (int i = 0; i < 8; ++i) {
        int id = i * 256 + tid;
        int kk = id >> 6, nn = id & 63;
        Ws[kk][nn] = w1[(size_t)(kc * 32 + kk) * 512 + nt * 64 + nn];
      }
      __syncthreads();
      #pragma unroll
      for (int kk = 0; kk < 32; ++kk) {
        float a0 = Zs[ty*4+0][kk], a1 = Zs[ty*4+1][kk], a2 = Zs[ty*4+2][kk], a3 = Zs[ty*4+3][kk];
        float q0 = Ws[kk][tx*4+0], q1 = Ws[kk][tx*4+1], q2 = Ws[kk][tx*4+2], q3 = Ws[kk][tx*4+3];
        acc[0][0] += a0*q0; acc[0][1] += a0*q1; acc[0][2] += a0*q2; acc[0][3] += a0*q3;
        acc[1][0] += a1*q0; acc[1][1] += a1*q1; acc[1][2] += a1*q2; acc[1][3] += a1*q3;
        acc[2][0] += a2*q0; acc[2][1] += a2*q1; acc[2][2] += a2*q2; acc[2][3] += a2*q3;
        acc[3][0] += a3*q0; acc[3][1] += a3*q1; acc[3][2] += a3*q2; acc[3][3] += a3*q3;
      }
    }
    #pragma unroll
    for (int i = 0; i < 4; ++i) {
      float p = 0.f;
      #pragma unroll
      for (int j = 0; j < 4; ++j) {
        int n = nt * 64 + tx * 4 + j;
        float h = acc[i][j] + b1[n]; h = fmaxf(h, 0.f);
        p += h * w2[n];
      }
      atomicAdd(&outacc[ty * 4 + i], p);
    }
  }
  __syncthreads();
  if (tid < 64 && (ebase + tid) < E) out[ebase + tid] = outacc[tid] + b2[0];
}

extern "C" void kernel_launch(void* const* d_in, const int* in_sizes, int n_in,
                              void* d_out, int out_size, void* d_ws, size_t ws_size,
                              hipStream_t stream)
{
  const float* z_user  = (const float*)d_in[0];
  const float* z_movie = (const float*)d_in[1];
  const int*   erow    = (const int*)d_in[2];
  const int*   ecol    = (const int*)d_in[3];
  const float* w1      = (const float*)d_in[4];
  const float* b1      = (const float*)d_in[5];
  const float* w2      = (const float*)d_in[6];
  const float* b2      = (const float*)d_in[7];
  float* out = (float*)d_out;

  const int NU = in_sizes[0] / HDIM;   // 100000
  const int NM = in_sizes[1] / HDIM;   // 50000
  const int E  = in_sizes[2];          // 500000

  const size_t need = ((size_t)NU * HDIM + (size_t)NM * HDIM + (size_t)1024 * 512) * 2;
  if (ws_size >= need) {
    unsigned short* u1  = (unsigned short*)d_ws;
    unsigned short* m1  = u1 + (size_t)NU * HDIM;
    unsigned short* w1t = m1 + (size_t)NM * HDIM;
    const int nMB1 = (NU + BM - 1) / BM;
    const int nMB2 = (NM + BM - 1) / BM;
    k_w1t<<<(1024 * 512) / 256, 256, 0, stream>>>(w1, w1t);
    k_gemm<<<dim3(HDIM / BN, nMB1 + nMB2), 512, 0, stream>>>(z_user, NU, z_movie, NM, w1t, u1, m1, nMB1);
    k_edge<<<2048, 256, 0, stream>>>(erow, ecol, u1, m1, b1, w2, b2, out, E);
  } else {
    k_fallback<<<(E + 63) / 64, 256, 0, stream>>>(z_user, z_movie, erow, ecol, w1, b1, w2, b2, out, E);
  }
}

// Round 5
// 549.798 us; speedup vs baseline: 1.5567x; 1.5567x over previous
//
#include <hip/hip_runtime.h>
#include <hip/hip_bf16.h>

typedef __attribute__((ext_vector_type(8))) short bf16x8;
typedef __attribute__((ext_vector_type(4))) float f32x4;

#define HDIM 512
#define BM 128
#define BN 256
#define BK 64
#define BKP 72   // +8 bf16 pad -> row stride 144 B (16B-aligned, even 8-group spread for b128)

__device__ __forceinline__ unsigned short f2bf(float f) {
  unsigned u = __float_as_uint(f);
  u += 0x7fffu + ((u >> 16) & 1u);   // round-to-nearest-even
  return (unsigned short)(u >> 16);
}

__device__ __forceinline__ unsigned int pk_bf(float x, float y) {
  __hip_bfloat162 h = __float22bfloat162_rn(float2{x, y});
  union { __hip_bfloat162 b; unsigned int u; } cv; cv.b = h;
  return cv.u;
}

__device__ __forceinline__ float blo(unsigned int u) { return __uint_as_float(u << 16); }
__device__ __forceinline__ float bhi(unsigned int u) { return __uint_as_float(u & 0xffff0000u); }

// w1 [1024 k][512 n] fp32 -> w1t [512 n][1024 k] bf16, LDS-tiled transpose.
// Old version wrote 2B elements at stride 2048B (fully uncoalesced scatter,
// est. ~100-150us hidden cost). Now: 64x64 tile staged in padded LDS;
// float4 coalesced reads, ushort4 (8B) coalesced writes -> ~3MB streamed, <10us.
__global__ __launch_bounds__(256) void k_w1t(const float* __restrict__ w1,
                                             unsigned short* __restrict__ w1t) {
  __shared__ float lds[64][65];
  const int tid = threadIdx.x;
  const int k0 = blockIdx.x * 64;    // 16 k-tiles
  const int n0 = blockIdx.y * 64;    // 8 n-tiles
  const int tr = tid >> 4, tc = tid & 15;
  #pragma unroll
  for (int p = 0; p < 4; ++p) {
    int row = p * 16 + tr;           // k-local
    const float4 v = *(const float4*)&w1[(size_t)(k0 + row) * 512 + n0 + tc * 4];
    lds[row][tc * 4 + 0] = v.x; lds[row][tc * 4 + 1] = v.y;
    lds[row][tc * 4 + 2] = v.z; lds[row][tc * 4 + 3] = v.w;
  }
  __syncthreads();
  #pragma unroll
  for (int p = 0; p < 4; ++p) {
    int n = p * 16 + tr;             // n-local
    int kq = tc * 4;                 // k-local
    ushort4 o;
    o.x = f2bf(lds[kq + 0][n]); o.y = f2bf(lds[kq + 1][n]);
    o.z = f2bf(lds[kq + 2][n]); o.w = f2bf(lds[kq + 3][n]);
    *(ushort4*)&w1t[(size_t)(n0 + n) * 1024 + k0 + kq] = o;
  }
}

// C[M,512](bf16) = A[M,512](fp32) @ w1t[:, koff:koff+512]^T   (bf16 MFMA, fp32 acc)
// Round-3 measured-best structure (170us): 128x256 tile, 8 waves 2x4, 54KB
// single-buffered LDS + T14 async-STAGE split (tile k+1 global->reg loads issue
// before tile k's compute; reg->LDS commit after the next barrier).
// NOTE: register-locked at 64 VGPR + 64 AGPR = 128/wave -> exactly 2 blocks/CU;
// any deeper prefetch (+32 regs) would halve occupancy. Do not add reg state.
__global__ __launch_bounds__(512) void k_gemm(
    const float* __restrict__ zu, int MU,
    const float* __restrict__ zm, int MM,
    const unsigned short* __restrict__ w1t,
    unsigned short* __restrict__ u1, unsigned short* __restrict__ m1,
    int nMB1)
{
  __shared__ unsigned short As[BM][BKP];   // 18 KB
  __shared__ unsigned short Bs[BN][BKP];   // 36 KB
  const int tid  = threadIdx.x;
  const int lane = tid & 63;
  const int wid  = tid >> 6;                  // 0..7
  const int wm = wid & 1, wn = wid >> 1;      // 2 x 4 wave grid
  const int lm = lane & 15, lq = lane >> 4;

  const float* A; unsigned short* C; int M, koff, mb = blockIdx.y;
  if (mb < nMB1) { A = zu; C = u1; M = MU; koff = 0; }
  else           { A = zm; C = m1; M = MM; koff = HDIM; mb -= nMB1; }
  const int nbase = blockIdx.x * BN;          // N-blocks fastest (2 of them)
  const int mbase = mb * BM;

  // ---- loop-invariant staging offsets ----
  int aoff[4]; unsigned int alds[4];
  #pragma unroll
  for (int i = 0; i < 4; ++i) {
    int fid = i * 512 + tid;
    int r = fid >> 4, c4 = fid & 15;
    int row = mbase + r; if (row > M - 1) row = M - 1;
    aoff[i] = row * HDIM + c4 * 4;            // element offset into A
    alds[i] = r * (BKP >> 1) + c4 * 2;        // dword index into As
  }
  int boff[4]; unsigned short* blds[4];
  #pragma unroll
  for (int i = 0; i < 4; ++i) {
    int cid = i * 512 + tid;
    int r = cid >> 3, c8 = cid & 7;
    boff[i] = (nbase + r) * 1024 + koff + c8 * 8;
    blds[i] = &Bs[r][c8 * 8];
  }
  unsigned int* Asw = (unsigned int*)&As[0][0];

  f32x4 acc[4][4];
  #pragma unroll
  for (int i = 0; i < 4; ++i)
    #pragma unroll
    for (int j = 0; j < 4; ++j) acc[i][j] = (f32x4){0.f, 0.f, 0.f, 0.f};

  // ---- prologue: tile 0 -> registers ----
  float4 areg[4]; bf16x8 breg[4];
  #pragma unroll
  for (int i = 0; i < 4; ++i) areg[i] = *(const float4*)&A[(size_t)aoff[i]];
  #pragma unroll
  for (int i = 0; i < 4; ++i) breg[i] = *(const bf16x8*)&w1t[(size_t)boff[i]];

  for (int kb = 0; kb < HDIM / BK; ++kb) {
    __syncthreads();                          // previous compute done reading LDS
    // commit staged regs -> LDS (A: packed RNE fp32->bf16)
    #pragma unroll
    for (int i = 0; i < 4; ++i) {
      Asw[alds[i]]     = pk_bf(areg[i].x, areg[i].y);
      Asw[alds[i] + 1] = pk_bf(areg[i].z, areg[i].w);
    }
    #pragma unroll
    for (int i = 0; i < 4; ++i) *(bf16x8*)blds[i] = breg[i];
    __syncthreads();                          // LDS tile kb visible
    // issue tile kb+1 loads -- latency hides under the MFMA phase below
    if (kb < HDIM / BK - 1) {
      const int k1 = (kb + 1) * BK;
      #pragma unroll
      for (int i = 0; i < 4; ++i) areg[i] = *(const float4*)&A[(size_t)(aoff[i] + k1)];
      #pragma unroll
      for (int i = 0; i < 4; ++i) breg[i] = *(const bf16x8*)&w1t[(size_t)(boff[i] + k1)];
    }
    // compute tile kb
    #pragma unroll
    for (int ks = 0; ks < 2; ++ks) {
      bf16x8 af[4], bfr[4];
      #pragma unroll
      for (int t = 0; t < 4; ++t) {
        af[t]  = *(const bf16x8*)&As[wm * 64 + t * 16 + lm][ks * 32 + lq * 8];
        bfr[t] = *(const bf16x8*)&Bs[wn * 64 + t * 16 + lm][ks * 32 + lq * 8];
      }
      #pragma unroll
      for (int mi = 0; mi < 4; ++mi)
        #pragma unroll
        for (int ni = 0; ni < 4; ++ni)
          acc[mi][ni] = __builtin_amdgcn_mfma_f32_16x16x32_bf16(af[mi], bfr[ni], acc[mi][ni], 0, 0, 0);
    }
  }
  // epilogue: C/D layout col=lane&15, row=(lane>>4)*4+reg  (m89-verified)
  #pragma unroll
  for (int mi = 0; mi < 4; ++mi)
    #pragma unroll
    for (int ni = 0; ni < 4; ++ni)
      #pragma unroll
      for (int r = 0; r < 4; ++r) {
        int rg = mbase + wm * 64 + mi * 16 + lq * 4 + r;
        int cg = nbase + wn * 64 + ni * 16 + lm;
        if (rg < M) C[(size_t)rg * HDIM + cg] = f2bf(acc[mi][ni][r]);
      }
}

// per edge: out = relu(U[row]+M[col]+b1) . w2 + b2 ; one wave, 4 edges/iter
// (8 gather loads in flight; measured ~135us vs 161 for 2-edge version)
__global__ __launch_bounds__(256) void k_edge(const int* __restrict__ er, const int* __restrict__ ec,
    const unsigned short* __restrict__ u1, const unsigned short* __restrict__ m1,
    const float* __restrict__ b1, const float* __restrict__ w2, const float* __restrict__ b2,
    float* __restrict__ out, int E)
{
  const int lane = threadIdx.x & 63;
  const int gwid = blockIdx.x * 4 + (threadIdx.x >> 6);
  const int nw   = gridDim.x * 4;
  const float4 b1a = *(const float4*)&b1[lane * 8];
  const float4 b1b = *(const float4*)&b1[lane * 8 + 4];
  const float4 w2a = *(const float4*)&w2[lane * 8];
  const float4 w2b = *(const float4*)&w2[lane * 8 + 4];
  const float bias2 = b2[0];
  for (int e = gwid * 4; e < E; e += nw * 4) {
    if (e + 3 < E) {
      uint4 ua[4], va[4];
      #pragma unroll
      for (int j = 0; j < 4; ++j) {
        ua[j] = *(const uint4*)&u1[(size_t)er[e + j] * HDIM + lane * 8];
        va[j] = *(const uint4*)&m1[(size_t)ec[e + j] * HDIM + lane * 8];
      }
      float p[4];
      #pragma unroll
      for (int j = 0; j < 4; ++j) {
        float pj = 0.f, s;
        s = blo(ua[j].x) + blo(va[j].x) + b1a.x; s = fmaxf(s, 0.f); pj += s * w2a.x;
        s = bhi(ua[j].x) + bhi(va[j].x) + b1a.y; s = fmaxf(s, 0.f); pj += s * w2a.y;
        s = blo(ua[j].y) + blo(va[j].y) + b1a.z; s = fmaxf(s, 0.f); pj += s * w2a.z;
        s = bhi(ua[j].y) + bhi(va[j].y) + b1a.w; s = fmaxf(s, 0.f); pj += s * w2a.w;
        s = blo(ua[j].z) + blo(va[j].z) + b1b.x; s = fmaxf(s, 0.f); pj += s * w2b.x;
        s = bhi(ua[j].z) + bhi(va[j].z) + b1b.y; s = fmaxf(s, 0.f); pj += s * w2b.y;
        s = blo(ua[j].w) + blo(va[j].w) + b1b.z; s = fmaxf(s, 0.f); pj += s * w2b.z;
        s = bhi(ua[j].w) + bhi(va[j].w) + b1b.w; s = fmaxf(s, 0.f); pj += s * w2b.w;
        p[j] = pj;
      }
      #pragma unroll
      for (int off = 32; off > 0; off >>= 1)
        #pragma unroll
        for (int j = 0; j < 4; ++j) p[j] += __shfl_down(p[j], off, 64);
      if (lane == 0)
        *(float4*)&out[e] = float4{p[0] + bias2, p[1] + bias2, p[2] + bias2, p[3] + bias2};
    } else {
      for (int j = 0; j < 4 && e + j < E; ++j) {
        const uint4 ua = *(const uint4*)&u1[(size_t)er[e + j] * HDIM + lane * 8];
        const uint4 va = *(const uint4*)&m1[(size_t)ec[e + j] * HDIM + lane * 8];
        float pj = 0.f, s;
        s = blo(ua.x) + blo(va.x) + b1a.x; s = fmaxf(s, 0.f); pj += s * w2a.x;
        s = bhi(ua.x) + bhi(va.x) + b1a.y; s = fmaxf(s, 0.f); pj += s * w2a.y;
        s = blo(ua.y) + blo(va.y) + b1a.z; s = fmaxf(s, 0.f); pj += s * w2a.z;
        s = bhi(ua.y) + bhi(va.y) + b1a.w; s = fmaxf(s, 0.f); pj += s * w2a.w;
        s = blo(ua.z) + blo(va.z) + b1b.x; s = fmaxf(s, 0.f); pj += s * w2b.x;
        s = bhi(ua.z) + bhi(va.z) + b1b.y; s = fmaxf(s, 0.f); pj += s * w2b.y;
        s = blo(ua.w) + blo(va.w) + b1b.z; s = fmaxf(s, 0.f); pj += s * w2b.z;
        s = bhi(ua.w) + bhi(va.w) + b1b.w; s = fmaxf(s, 0.f); pj += s * w2b.w;
        #pragma unroll
        for (int off = 32; off > 0; off >>= 1) pj += __shfl_down(pj, off, 64);
        if (lane == 0) out[e + j] = pj + bias2;
      }
    }
  }
}

// Correct-but-slow fp32 fallback (only if ws_size too small): fused tiled GEMM
__global__ __launch_bounds__(256) void k_fallback(const float* __restrict__ zu, const float* __restrict__ zm,
    const int* __restrict__ er, const int* __restrict__ ec, const float* __restrict__ w1,
    const float* __restrict__ b1, const float* __restrict__ w2, const float* __restrict__ b2,
    float* __restrict__ out, int E)
{
  __shared__ float Zs[64][33];
  __shared__ float Ws[32][65];
  __shared__ float outacc[64];
  __shared__ int ridx[64], cidx[64];
  const int tid = threadIdx.x;
  const int ebase = blockIdx.x * 64;
  if (tid < 64) {
    int e = ebase + tid; if (e > E - 1) e = E - 1;
    ridx[tid] = er[e]; cidx[tid] = ec[e];
    outacc[tid] = 0.f;
  }
  const int tx = tid & 15, ty = tid >> 4;
  for (int nt = 0; nt < 8; ++nt) {
    float acc[4][4] = {};
    for (int kc = 0; kc < 32; ++kc) {
      __syncthreads();
      #pragma unroll
      for (int i = 0; i < 8; ++i) {
        int id = i * 256 + tid;
        int rr = id >> 5, cc = id & 31;
        int k = kc * 32 + cc;
        Zs[rr][cc] = (k < 512) ? zu[(size_t)ridx[rr] * 512 + k]
                               : zm[(size_t)cidx[rr] * 512 + (k - 512)];
      }
      #pragma unroll
      for (int i = 0; i < 8; ++i) {
        int id = i * 256 + tid;
        int kk = id >> 6, nn = id & 63;
        Ws[kk][nn] = w1[(size_t)(kc * 32 + kk) * 512 + nt * 64 + nn];
      }
      __syncthreads();
      #pragma unroll
      for (int kk = 0; kk < 32; ++kk) {
        float a0 = Zs[ty*4+0][kk], a1 = Zs[ty*4+1][kk], a2 = Zs[ty*4+2][kk], a3 = Zs[ty*4+3][kk];
        float q0 = Ws[kk][tx*4+0], q1 = Ws[kk][tx*4+1], q2 = Ws[kk][tx*4+2], q3 = Ws[kk][tx*4+3];
        acc[0][0] += a0*q0; acc[0][1] += a0*q1; acc[0][2] += a0*q2; acc[0][3] += a0*q3;
        acc[1][0] += a1*q0; acc[1][1] += a1*q1; acc[1][2] += a1*q2; acc[1][3] += a1*q3;
        acc[2][0] += a2*q0; acc[2][1] += a2*q1; acc[2][2] += a2*q2; acc[2][3] += a2*q3;
        acc[3][0] += a3*q0; acc[3][1] += a3*q1; acc[3][2] += a3*q2; acc[3][3] += a3*q3;
      }
    }
    #pragma unroll
    for (int i = 0; i < 4; ++i) {
      float p = 0.f;
      #pragma unroll
      for (int j = 0; j < 4; ++j) {
        int n = nt * 64 + tx * 4 + j;
        float h = acc[i][j] + b1[n]; h = fmaxf(h, 0.f);
        p += h * w2[n];
      }
      atomicAdd(&outacc[ty * 4 + i], p);
    }
  }
  __syncthreads();
  if (tid < 64 && (ebase + tid) < E) out[ebase + tid] = outacc[tid] + b2[0];
}

extern "C" void kernel_launch(void* const* d_in, const int* in_sizes, int n_in,
                              void* d_out, int out_size, void* d_ws, size_t ws_size,
                              hipStream_t stream)
{
  const float* z_user  = (const float*)d_in[0];
  const float* z_movie = (const float*)d_in[1];
  const int*   erow    = (const int*)d_in[2];
  const int*   ecol    = (const int*)d_in[3];
  const float* w1      = (const float*)d_in[4];
  const float* b1      = (const float*)d_in[5];
  const float* w2      = (const float*)d_in[6];
  const float* b2      = (const float*)d_in[7];
  float* out = (float*)d_out;

  const int NU = in_sizes[0] / HDIM;   // 100000
  const int NM = in_sizes[1] / HDIM;   // 50000
  const int E  = in_sizes[2];          // 500000

  const size_t need = ((size_t)NU * HDIM + (size_t)NM * HDIM + (size_t)1024 * 512) * 2;
  if (ws_size >= need) {
    unsigned short* u1  = (unsigned short*)d_ws;
    unsigned short* m1  = u1 + (size_t)NU * HDIM;
    unsigned short* w1t = m1 + (size_t)NM * HDIM;
    const int nMB1 = (NU + BM - 1) / BM;
    const int nMB2 = (NM + BM - 1) / BM;
    k_w1t<<<dim3(16, 8), 256, 0, stream>>>(w1, w1t);
    k_gemm<<<dim3(HDIM / BN, nMB1 + nMB2), 512, 0, stream>>>(z_user, NU, z_movie, NM, w1t, u1, m1, nMB1);
    k_edge<<<2048, 256, 0, stream>>>(erow, ecol, u1, m1, b1, w2, b2, out, E);
  } else {
    k_fallback<<<(E + 63) / 64, 256, 0, stream>>>(z_user, z_movie, erow, ecol, w1, b1, w2, b2, out, E);
  }
}